// Round 1
// baseline (298.055 us; speedup 1.0000x reference)
//
#include <hip/hip_runtime.h>

typedef unsigned short u16;
typedef __bf16 bf16x8 __attribute__((ext_vector_type(8)));
typedef float f32x4 __attribute__((ext_vector_type(4)));
typedef unsigned short u16x8 __attribute__((ext_vector_type(8)));

#define HID 2880
#define QKV_N 5120
#define SEQ 2048
#define ATTN_K 4096
#define OUTD 2880
#define WO_NPAD 2944
#define SCALE 0.125f
#define NEGINF -1e30f

__device__ __forceinline__ u16 f2bf(float f) {
  unsigned int u = __builtin_bit_cast(unsigned int, f);
  u = (u + 0x7FFFu + ((u >> 16) & 1u)) >> 16;
  return (u16)u;
}

#define MFMA16(a, b, c) __builtin_amdgcn_mfma_f32_16x16x32_bf16((a), (b), (c), 0, 0, 0)

// ---------------- RoPE table: tab[s*32+i] = {cos, sin} ----------------
__global__ __launch_bounds__(256) void k_rope_table(const int* __restrict__ pos,
                                                    float2* __restrict__ tab) {
  int t = blockIdx.x * 256 + threadIdx.x;  // 65536 = 2048*32
  int s = t >> 5, i = t & 31;
  float freq = powf(150000.0f, -(float)i * (1.0f / 32.0f));
  float ang = (float)pos[s] * freq;
  float sv, cv;
  sincosf(ang, &sv, &cv);
  tab[t] = make_float2(cv, sv);
}

// ---------------- f32 -> bf16 convert (vectorized) ----------------
__global__ __launch_bounds__(256) void k_convert_hs(const float* __restrict__ in,
                                                    u16* __restrict__ out, int n4) {
  int i = blockIdx.x * 256 + threadIdx.x;
  if (i >= n4) return;
  float4 v = ((const float4*)in)[i];
  ushort4 o;
  o.x = f2bf(v.x); o.y = f2bf(v.y); o.z = f2bf(v.z); o.w = f2bf(v.w);
  ((ushort4*)out)[i] = o;
}

// ------------- transpose + convert: in f32 [Kd][Nd] -> out bf16 [Npad][Kd] -------------
__global__ __launch_bounds__(256) void k_transpose(const float* __restrict__ in,
                                                   u16* __restrict__ out,
                                                   int Kd, int Nd, int Npad) {
  __shared__ float tile[32][33];
  int n0 = blockIdx.x * 32, k0 = blockIdx.y * 32;
  int c = threadIdx.x & 31, r0 = threadIdx.x >> 5;
#pragma unroll
  for (int j = 0; j < 4; j++) {
    int r = r0 + j * 8;
    float v = 0.f;
    if (n0 + c < Nd) v = in[(size_t)(k0 + r) * Nd + n0 + c];
    tile[r][c] = v;
  }
  __syncthreads();
#pragma unroll
  for (int j = 0; j < 4; j++) {
    int rr = r0 + j * 8;           // local n
    int n = n0 + rr;
    if (n < Npad) out[(size_t)n * Kd + k0 + c] = f2bf(tile[c][rr]);
  }
}

// ---------------- RoPE in-place on Q+K regions of qkv ----------------
__global__ __launch_bounds__(256) void k_rope_apply(float* __restrict__ qkv,
                                                    const float2* __restrict__ tab) {
  int t = blockIdx.x * 256 + threadIdx.x;  // 2048*72*32
  int i = t & 31;
  int t2 = t >> 5;
  int h = t2 % 72;
  int s = t2 / 72;
  float* p = qkv + (size_t)s * QKV_N + h * 64 + i;
  float x1 = p[0], x2 = p[32];
  float2 cs = tab[s * 32 + i];
  p[0] = x1 * cs.x - x2 * cs.y;
  p[32] = x2 * cs.x + x1 * cs.y;
}

// ---------------- bf16 MFMA GEMM: C[m][n] = sum_k A[m][k]*B[n][k] + bias[n] ----------------
// A: M x K bf16 row-major. B: Npad x K bf16 row-major (i.e. B^T). C: f32, ldc.
template <bool GUARD_N>
__global__ __launch_bounds__(256, 2) void k_gemm(const u16* __restrict__ A,
                                                 const u16* __restrict__ B,
                                                 const float* __restrict__ bias,
                                                 float* __restrict__ C,
                                                 int K, int Nlog, int ldc) {
  __shared__ u16 Alds[128 * 32];
  __shared__ u16 Blds[128 * 32];
  const int tid = threadIdx.x;
  const int lane = tid & 63, wave = tid >> 6;
  const int wm = wave >> 1, wn = wave & 1;
  const int m0 = blockIdx.x * 128, n0 = blockIdx.y * 128;
  const int r = tid >> 1, hh = tid & 1;
  const int lr = lane & 15, lg = lane >> 4;

  f32x4 acc[4][4];
  f32x4 zz = {0.f, 0.f, 0.f, 0.f};
#pragma unroll
  for (int a = 0; a < 4; a++)
#pragma unroll
    for (int b = 0; b < 4; b++) acc[a][b] = zz;

  const u16* ga = A + (size_t)(m0 + r) * K + hh * 16;
  const u16* gb = B + (size_t)(n0 + r) * K + hh * 16;
  u16* wa = &Alds[r * 32 + hh * 16];
  u16* wb = &Blds[r * 32 + hh * 16];
  const u16* pa = &Alds[(wm * 64 + lr) * 32 + lg * 8];
  const u16* pb = &Blds[(wn * 64 + lr) * 32 + lg * 8];

  u16x8 a0 = *(const u16x8*)(ga);
  u16x8 a1 = *(const u16x8*)(ga + 8);
  u16x8 b0 = *(const u16x8*)(gb);
  u16x8 b1 = *(const u16x8*)(gb + 8);

  for (int kt = 0; kt < K; kt += 32) {
    __syncthreads();
    *(u16x8*)wa = a0;
    *(u16x8*)(wa + 8) = a1;
    *(u16x8*)wb = b0;
    *(u16x8*)(wb + 8) = b1;
    __syncthreads();

    bf16x8 af[4], bfm[4];
#pragma unroll
    for (int mi = 0; mi < 4; mi++) af[mi] = *(const bf16x8*)(pa + mi * 512);
#pragma unroll
    for (int ni = 0; ni < 4; ni++) bfm[ni] = *(const bf16x8*)(pb + ni * 512);

    int kn = (kt + 32 < K) ? kt + 32 : kt;  // prefetch (dummy on last iter)
    a0 = *(const u16x8*)(ga + kn);
    a1 = *(const u16x8*)(ga + kn + 8);
    b0 = *(const u16x8*)(gb + kn);
    b1 = *(const u16x8*)(gb + kn + 8);

#pragma unroll
    for (int mi = 0; mi < 4; mi++)
#pragma unroll
      for (int ni = 0; ni < 4; ni++)
        acc[mi][ni] = MFMA16(af[mi], bfm[ni], acc[mi][ni]);
  }

#pragma unroll
  for (int mi = 0; mi < 4; mi++)
#pragma unroll
    for (int ni = 0; ni < 4; ni++) {
      int row = m0 + wm * 64 + mi * 16 + lg * 4;
      int col = n0 + wn * 64 + ni * 16 + lr;
      if (!GUARD_N || col < Nlog) {
        float bv = bias[col];
#pragma unroll
        for (int rg = 0; rg < 4; rg++)
          C[(size_t)(row + rg) * ldc + col] = acc[mi][ni][rg] + bv;
      }
    }
}

// ---------------- sliding-window attention with sinks ----------------
// grid (64 qtiles, 8 kv heads), 512 threads (8 waves = 8 G-heads), QB=32, KEYS=160
__global__ __launch_bounds__(512, 2) void k_attn(const float* __restrict__ qkv,
                                                 const float* __restrict__ sinks,
                                                 u16* __restrict__ out) {
  __shared__ u16 Klds[160 * 64];     // XOR-swizzled rows
  __shared__ u16 Vt[64 * 168];       // V transposed [d][key], padded
  __shared__ u16 Pslab[8 * 32 * 40]; // per-wave P bounce, padded rows
  const int hk = blockIdx.y;
  const int s0 = blockIdx.x * 32;
  const int kb = s0 - 127;
  const int tid = threadIdx.x;
  const int lane = tid & 63, w = tid >> 6;
  const int lr = lane & 15, lg = lane >> 4;

  // ---- stage K (roped) into swizzled LDS ----
  for (int ch = tid; ch < 160 * 8; ch += 512) {
    int key = ch >> 3, c = ch & 7;
    int kidx = kb + key;
    u16x8 val = {0, 0, 0, 0, 0, 0, 0, 0};
    if (kidx >= 0 && kidx < SEQ) {
      const float4* g = (const float4*)(qkv + (size_t)kidx * QKV_N + 4096 + hk * 64 + c * 8);
      float4 f0 = g[0], f1 = g[1];
      val[0] = f2bf(f0.x); val[1] = f2bf(f0.y); val[2] = f2bf(f0.z); val[3] = f2bf(f0.w);
      val[4] = f2bf(f1.x); val[5] = f2bf(f1.y); val[6] = f2bf(f1.z); val[7] = f2bf(f1.w);
    }
    int off = (key * 128 + c * 16) ^ ((key & 7) << 4);
    *(u16x8*)((char*)Klds + off) = val;
  }
  // ---- stage V transposed ----
  for (int e4 = tid; e4 < 160 * 16; e4 += 512) {
    int key = e4 >> 4, d0 = (e4 & 15) * 4;
    int kidx = kb + key;
    float4 v = make_float4(0.f, 0.f, 0.f, 0.f);
    if (kidx >= 0 && kidx < SEQ)
      v = *(const float4*)(qkv + (size_t)kidx * QKV_N + 4608 + hk * 64 + d0);
    Vt[(d0 + 0) * 168 + key] = f2bf(v.x);
    Vt[(d0 + 1) * 168 + key] = f2bf(v.y);
    Vt[(d0 + 2) * 168 + key] = f2bf(v.z);
    Vt[(d0 + 3) * 168 + key] = f2bf(v.w);
  }

  // ---- load Q fragments (roped) straight to registers ----
  const int head = hk * 8 + w;
  bf16x8 qf[2][2];
#pragma unroll
  for (int rt = 0; rt < 2; rt++)
#pragma unroll
    for (int ks = 0; ks < 2; ks++) {
      const float* g = qkv + (size_t)(s0 + rt * 16 + lr) * QKV_N + head * 64 + ks * 32 + lg * 8;
      float4 f0 = *(const float4*)g, f1 = *(const float4*)(g + 4);
      u16x8 u;
      u[0] = f2bf(f0.x); u[1] = f2bf(f0.y); u[2] = f2bf(f0.z); u[3] = f2bf(f0.w);
      u[4] = f2bf(f1.x); u[5] = f2bf(f1.y); u[6] = f2bf(f1.z); u[7] = f2bf(f1.w);
      qf[rt][ks] = __builtin_bit_cast(bf16x8, u);
    }
  __syncthreads();

  // ---- QK^T ----
  f32x4 sc[2][10];
  f32x4 zz = {0.f, 0.f, 0.f, 0.f};
#pragma unroll
  for (int rt = 0; rt < 2; rt++)
#pragma unroll
    for (int nt = 0; nt < 10; nt++) sc[rt][nt] = zz;
#pragma unroll
  for (int nt = 0; nt < 10; nt++) {
    int key = nt * 16 + lr;
#pragma unroll
    for (int ks = 0; ks < 2; ks++) {
      int off = (key * 128 + ks * 64 + lg * 16) ^ ((key & 7) << 4);
      bf16x8 kf = *(const bf16x8*)((const char*)Klds + off);
      sc[0][nt] = MFMA16(qf[0][ks], kf, sc[0][nt]);
      sc[1][nt] = MFMA16(qf[1][ks], kf, sc[1][nt]);
    }
  }

  // ---- mask + scale ----
#pragma unroll
  for (int rt = 0; rt < 2; rt++)
#pragma unroll
    for (int nt = 0; nt < 10; nt++)
#pragma unroll
      for (int rg = 0; rg < 4; rg++) {
        int qq = rt * 16 + lg * 4 + rg;
        int j = nt * 16 + lr;
        bool valid = (j >= qq) && (j <= qq + 127) && ((kb + j) >= 0);
        sc[rt][nt][rg] = valid ? sc[rt][nt][rg] * SCALE : NEGINF;
      }

  // ---- softmax (rows spread over 16-lane groups) ----
  const float sink = sinks[head];
  float den[2][4];
#pragma unroll
  for (int rt = 0; rt < 2; rt++)
#pragma unroll
    for (int rg = 0; rg < 4; rg++) {
      float m = NEGINF;
#pragma unroll
      for (int nt = 0; nt < 10; nt++) m = fmaxf(m, sc[rt][nt][rg]);
#pragma unroll
      for (int x = 1; x < 16; x <<= 1) m = fmaxf(m, __shfl_xor(m, x, 64));
      m = fmaxf(m, sink);
      float sum = 0.f;
#pragma unroll
      for (int nt = 0; nt < 10; nt++) {
        float p = __expf(sc[rt][nt][rg] - m);
        sc[rt][nt][rg] = p;
        sum += p;
      }
#pragma unroll
      for (int x = 1; x < 16; x <<= 1) sum += __shfl_xor(sum, x, 64);
      den[rt][rg] = sum + __expf(sink - m);
    }

  // ---- PV ----
  f32x4 oacc[2][4];
#pragma unroll
  for (int rt = 0; rt < 2; rt++)
#pragma unroll
    for (int dn = 0; dn < 4; dn++) oacc[rt][dn] = zz;
  u16* slab = &Pslab[w * 32 * 40];
#pragma unroll
  for (int kt = 0; kt < 5; kt++) {
#pragma unroll
    for (int rt = 0; rt < 2; rt++)
#pragma unroll
      for (int j2 = 0; j2 < 2; j2++)
#pragma unroll
        for (int rg = 0; rg < 4; rg++)
          slab[(rt * 16 + lg * 4 + rg) * 40 + j2 * 16 + lr] = f2bf(sc[rt][kt * 2 + j2][rg]);
    asm volatile("s_waitcnt lgkmcnt(0)" ::: "memory");
    __builtin_amdgcn_sched_barrier(0);
    bf16x8 pf0 = *(const bf16x8*)&slab[lr * 40 + lg * 8];
    bf16x8 pf1 = *(const bf16x8*)&slab[(16 + lr) * 40 + lg * 8];
#pragma unroll
    for (int dn = 0; dn < 4; dn++) {
      bf16x8 vf = *(const bf16x8*)&Vt[(dn * 16 + lr) * 168 + kt * 32 + lg * 8];
      oacc[0][dn] = MFMA16(pf0, vf, oacc[0][dn]);
      oacc[1][dn] = MFMA16(pf1, vf, oacc[1][dn]);
    }
  }

  // ---- write normalized output (bf16 for GEMM2) ----
#pragma unroll
  for (int rt = 0; rt < 2; rt++)
#pragma unroll
    for (int dn = 0; dn < 4; dn++)
#pragma unroll
      for (int rg = 0; rg < 4; rg++) {
        int s = s0 + rt * 16 + lg * 4 + rg;
        float val = oacc[rt][dn][rg] / den[rt][rg];
        out[(size_t)s * ATTN_K + head * 64 + dn * 16 + lr] = f2bf(val);
      }
}

extern "C" void kernel_launch(void* const* d_in, const int* in_sizes, int n_in,
                              void* d_out, int out_size, void* d_ws, size_t ws_size,
                              hipStream_t stream) {
  const float* hs = (const float*)d_in[0];
  const int* pos = (const int*)d_in[1];
  const float* wqkv = (const float*)d_in[2];
  const float* bqkv = (const float*)d_in[3];
  const float* wo = (const float*)d_in[4];
  const float* bo = (const float*)d_in[5];
  const float* sinks = (const float*)d_in[6];
  float* out = (float*)d_out;

  char* ws = (char*)d_ws;
  float* qkv = (float*)(ws + 0);                 // 2048*5120*4  = 41,943,040
  u16* hsb = (u16*)(ws + 41943040);              // 2048*2880*2  = 11,796,480
  u16* wqkvT = (u16*)(ws + 53739520);            // 5120*2880*2  = 29,491,200
  u16* woT = (u16*)(ws + 83230720);              // 2944*4096*2  = 24,117,248
  u16* attn = (u16*)(ws + 107347968);            // 2048*4096*2  = 16,777,216
  float2* tab = (float2*)(ws + 124125184);       // 2048*32*8    =    524,288

  k_rope_table<<<256, 256, 0, stream>>>(pos, tab);
  k_convert_hs<<<5760, 256, 0, stream>>>(hs, hsb, 1474560);
  k_transpose<<<dim3(160, 90), 256, 0, stream>>>(wqkv, wqkvT, 2880, 5120, 5120);
  k_transpose<<<dim3(92, 128), 256, 0, stream>>>(wo, woT, 4096, 2880, 2944);
  k_gemm<false><<<dim3(16, 40), 256, 0, stream>>>(hsb, wqkvT, bqkv, qkv, 2880, 5120, 5120);
  k_rope_apply<<<18432, 256, 0, stream>>>(qkv, tab);
  k_attn<<<dim3(64, 8), 512, 0, stream>>>(qkv, sinks, attn);
  k_gemm<true><<<dim3(16, 23), 256, 0, stream>>>(attn, woT, bo, out, 4096, 2880, 2880);
}

// Round 2
// 263.768 us; speedup vs baseline: 1.1300x; 1.1300x over previous
//
#include <hip/hip_runtime.h>

typedef unsigned short u16;
typedef __bf16 bf16x8 __attribute__((ext_vector_type(8)));
typedef float f32x4 __attribute__((ext_vector_type(4)));
typedef unsigned short u16x8 __attribute__((ext_vector_type(8)));

#define HID 2880
#define QKV_N 5120
#define SEQ 2048
#define ATTN_K 4096
#define OUTD 2880
#define WO_NPAD 2944
#define SCALE 0.125f
#define NEGINF -1e30f

__device__ __forceinline__ u16 f2bf(float f) {
  unsigned int u = __builtin_bit_cast(unsigned int, f);
  u = (u + 0x7FFFu + ((u >> 16) & 1u)) >> 16;
  return (u16)u;
}

#define MFMA16(a, b, c) __builtin_amdgcn_mfma_f32_16x16x32_bf16((a), (b), (c), 0, 0, 0)

// async global->LDS, 16B per lane; LDS dest = wave-uniform base + lane*16
__device__ __forceinline__ void gl_lds16(const u16* g, u16* l) {
  __builtin_amdgcn_global_load_lds(
      (const __attribute__((address_space(1))) unsigned int*)(const void*)g,
      (__attribute__((address_space(3))) unsigned int*)(void*)l, 16, 0, 0);
}

// ---------------- RoPE table: tab[s*32+i] = {cos, sin} ----------------
__global__ __launch_bounds__(256) void k_rope_table(const int* __restrict__ pos,
                                                    float2* __restrict__ tab) {
  int t = blockIdx.x * 256 + threadIdx.x;  // 65536 = 2048*32
  int s = t >> 5, i = t & 31;
  float freq = powf(150000.0f, -(float)i * (1.0f / 32.0f));
  float ang = (float)pos[s] * freq;
  float sv, cv;
  sincosf(ang, &sv, &cv);
  tab[t] = make_float2(cv, sv);
}

// ---------------- f32 -> bf16 convert (vectorized) ----------------
__global__ __launch_bounds__(256) void k_convert_hs(const float* __restrict__ in,
                                                    u16* __restrict__ out, int n4) {
  int i = blockIdx.x * 256 + threadIdx.x;
  if (i >= n4) return;
  float4 v = ((const float4*)in)[i];
  ushort4 o;
  o.x = f2bf(v.x); o.y = f2bf(v.y); o.z = f2bf(v.z); o.w = f2bf(v.w);
  ((ushort4*)out)[i] = o;
}

// ------------- transpose + convert: in f32 [Kd][Nd] -> out bf16 [Npad][Kd] -------------
__global__ __launch_bounds__(256) void k_transpose(const float* __restrict__ in,
                                                   u16* __restrict__ out,
                                                   int Kd, int Nd, int Npad) {
  __shared__ float tile[32][33];
  int n0 = blockIdx.x * 32, k0 = blockIdx.y * 32;
  int c = threadIdx.x & 31, r0 = threadIdx.x >> 5;
#pragma unroll
  for (int j = 0; j < 4; j++) {
    int r = r0 + j * 8;
    float v = 0.f;
    if (n0 + c < Nd) v = in[(size_t)(k0 + r) * Nd + n0 + c];
    tile[r][c] = v;
  }
  __syncthreads();
#pragma unroll
  for (int j = 0; j < 4; j++) {
    int rr = r0 + j * 8;           // local n
    int n = n0 + rr;
    if (n < Npad) out[(size_t)n * Kd + k0 + c] = f2bf(tile[c][rr]);
  }
}

// ---------------- RoPE in-place on Q+K regions of qkv ----------------
__global__ __launch_bounds__(256) void k_rope_apply(float* __restrict__ qkv,
                                                    const float2* __restrict__ tab) {
  int t = blockIdx.x * 256 + threadIdx.x;  // 2048*72*32
  int i = t & 31;
  int t2 = t >> 5;
  int h = t2 % 72;
  int s = t2 / 72;
  float* p = qkv + (size_t)s * QKV_N + h * 64 + i;
  float x1 = p[0], x2 = p[32];
  float2 cs = tab[s * 32 + i];
  p[0] = x1 * cs.x - x2 * cs.y;
  p[32] = x2 * cs.x + x1 * cs.y;
}

// ---------------- bf16 MFMA GEMM (m97 structure): C[m][n] = sum_k A[m][k]*B[n][k] + bias[n]
// A: M x K bf16 row-major. B: Npad x K bf16 row-major (i.e. B^T). C: f32, ldc.
// 128x128 tile, BK=32, 4 waves, global_load_lds dwordx4 staging, linear LDS.
template <bool GUARD_N>
__global__ __launch_bounds__(256, 2) void k_gemm(const u16* __restrict__ A,
                                                 const u16* __restrict__ B,
                                                 const float* __restrict__ bias,
                                                 float* __restrict__ C,
                                                 int K, int Nlog, int ldc) {
  __shared__ u16 Alds[128 * 32];
  __shared__ u16 Blds[128 * 32];
  const int tid = threadIdx.x;
  const int lane = tid & 63, wave = tid >> 6;
  const int wm = wave >> 1, wn = wave & 1;
  const int m0 = blockIdx.x * 128, n0 = blockIdx.y * 128;
  const int lr = lane & 15, lg = lane >> 4;

  f32x4 acc[4][4];
  f32x4 zz = {0.f, 0.f, 0.f, 0.f};
#pragma unroll
  for (int a = 0; a < 4; a++)
#pragma unroll
    for (int b = 0; b < 4; b++) acc[a][b] = zz;

  // staging addresses: wave w, round r covers rows w*16 + r*64 + lane/4, chunk lane&3
  const int srow = wave * 16 + (lane >> 2);
  const int schk = (lane & 3) * 8;
  const u16* gA0 = A + (size_t)(m0 + srow) * K + schk;
  const u16* gA1 = A + (size_t)(m0 + srow + 64) * K + schk;
  const u16* gB0 = B + (size_t)(n0 + srow) * K + schk;
  const u16* gB1 = B + (size_t)(n0 + srow + 64) * K + schk;
  u16* lA0 = &Alds[wave * 512];          // + lane*8 u16 done by HW
  u16* lA1 = &Alds[wave * 512 + 2048];
  u16* lB0 = &Blds[wave * 512];
  u16* lB1 = &Blds[wave * 512 + 2048];

  const u16* pa = &Alds[(wm * 64 + lr) * 32 + lg * 8];
  const u16* pb = &Blds[(wn * 64 + lr) * 32 + lg * 8];

  for (int kt = 0; kt < K; kt += 32) {
    gl_lds16(gA0 + kt, lA0);
    gl_lds16(gA1 + kt, lA1);
    gl_lds16(gB0 + kt, lB0);
    gl_lds16(gB1 + kt, lB1);
    __syncthreads();  // drains vmcnt(0): LDS tile ready

    bf16x8 af[4], bfm[4];
#pragma unroll
    for (int mi = 0; mi < 4; mi++) af[mi] = *(const bf16x8*)(pa + mi * 512);
#pragma unroll
    for (int ni = 0; ni < 4; ni++) bfm[ni] = *(const bf16x8*)(pb + ni * 512);

#pragma unroll
    for (int mi = 0; mi < 4; mi++)
#pragma unroll
      for (int ni = 0; ni < 4; ni++)
        acc[mi][ni] = MFMA16(af[mi], bfm[ni], acc[mi][ni]);
    __syncthreads();  // all waves done reading before next stage overwrites
  }

#pragma unroll
  for (int mi = 0; mi < 4; mi++)
#pragma unroll
    for (int ni = 0; ni < 4; ni++) {
      int row = m0 + wm * 64 + mi * 16 + lg * 4;
      int col = n0 + wn * 64 + ni * 16 + lr;
      if (!GUARD_N || col < Nlog) {
        float bv = bias[col];
#pragma unroll
        for (int rg = 0; rg < 4; rg++)
          C[(size_t)(row + rg) * ldc + col] = acc[mi][ni][rg] + bv;
      }
    }
}

// ---------------- sliding-window attention with sinks ----------------
// grid (64 qtiles, 8 kv heads), 512 threads (8 waves = 8 G-heads), QB=32, KEYS=160
__global__ __launch_bounds__(512, 2) void k_attn(const float* __restrict__ qkv,
                                                 const float* __restrict__ sinks,
                                                 u16* __restrict__ out) {
  __shared__ u16 Klds[160 * 64];     // XOR-swizzled rows
  __shared__ u16 Vt[64 * 168];       // V transposed [d][key], padded
  __shared__ u16 Pslab[8 * 32 * 40]; // per-wave P bounce, padded rows
  const int hk = blockIdx.y;
  const int s0 = blockIdx.x * 32;
  const int kb = s0 - 127;
  const int tid = threadIdx.x;
  const int lane = tid & 63, w = tid >> 6;
  const int lr = lane & 15, lg = lane >> 4;

  // ---- stage K (roped) into swizzled LDS ----
  for (int ch = tid; ch < 160 * 8; ch += 512) {
    int key = ch >> 3, c = ch & 7;
    int kidx = kb + key;
    u16x8 val = {0, 0, 0, 0, 0, 0, 0, 0};
    if (kidx >= 0 && kidx < SEQ) {
      const float4* g = (const float4*)(qkv + (size_t)kidx * QKV_N + 4096 + hk * 64 + c * 8);
      float4 f0 = g[0], f1 = g[1];
      val[0] = f2bf(f0.x); val[1] = f2bf(f0.y); val[2] = f2bf(f0.z); val[3] = f2bf(f0.w);
      val[4] = f2bf(f1.x); val[5] = f2bf(f1.y); val[6] = f2bf(f1.z); val[7] = f2bf(f1.w);
    }
    int off = (key * 128 + c * 16) ^ ((key & 7) << 4);
    *(u16x8*)((char*)Klds + off) = val;
  }
  // ---- stage V transposed ----
  for (int e4 = tid; e4 < 160 * 16; e4 += 512) {
    int key = e4 >> 4, d0 = (e4 & 15) * 4;
    int kidx = kb + key;
    float4 v = make_float4(0.f, 0.f, 0.f, 0.f);
    if (kidx >= 0 && kidx < SEQ)
      v = *(const float4*)(qkv + (size_t)kidx * QKV_N + 4608 + hk * 64 + d0);
    Vt[(d0 + 0) * 168 + key] = f2bf(v.x);
    Vt[(d0 + 1) * 168 + key] = f2bf(v.y);
    Vt[(d0 + 2) * 168 + key] = f2bf(v.z);
    Vt[(d0 + 3) * 168 + key] = f2bf(v.w);
  }

  // ---- load Q fragments (roped) straight to registers ----
  const int head = hk * 8 + w;
  bf16x8 qf[2][2];
#pragma unroll
  for (int rt = 0; rt < 2; rt++)
#pragma unroll
    for (int ks = 0; ks < 2; ks++) {
      const float* g = qkv + (size_t)(s0 + rt * 16 + lr) * QKV_N + head * 64 + ks * 32 + lg * 8;
      float4 f0 = *(const float4*)g, f1 = *(const float4*)(g + 4);
      u16x8 u;
      u[0] = f2bf(f0.x); u[1] = f2bf(f0.y); u[2] = f2bf(f0.z); u[3] = f2bf(f0.w);
      u[4] = f2bf(f1.x); u[5] = f2bf(f1.y); u[6] = f2bf(f1.z); u[7] = f2bf(f1.w);
      qf[rt][ks] = __builtin_bit_cast(bf16x8, u);
    }
  __syncthreads();

  // ---- QK^T ----
  f32x4 sc[2][10];
  f32x4 zz = {0.f, 0.f, 0.f, 0.f};
#pragma unroll
  for (int rt = 0; rt < 2; rt++)
#pragma unroll
    for (int nt = 0; nt < 10; nt++) sc[rt][nt] = zz;
#pragma unroll
  for (int nt = 0; nt < 10; nt++) {
    int key = nt * 16 + lr;
#pragma unroll
    for (int ks = 0; ks < 2; ks++) {
      int off = (key * 128 + ks * 64 + lg * 16) ^ ((key & 7) << 4);
      bf16x8 kf = *(const bf16x8*)((const char*)Klds + off);
      sc[0][nt] = MFMA16(qf[0][ks], kf, sc[0][nt]);
      sc[1][nt] = MFMA16(qf[1][ks], kf, sc[1][nt]);
    }
  }

  // ---- mask + scale ----
#pragma unroll
  for (int rt = 0; rt < 2; rt++)
#pragma unroll
    for (int nt = 0; nt < 10; nt++)
#pragma unroll
      for (int rg = 0; rg < 4; rg++) {
        int qq = rt * 16 + lg * 4 + rg;
        int j = nt * 16 + lr;
        bool valid = (j >= qq) && (j <= qq + 127) && ((kb + j) >= 0);
        sc[rt][nt][rg] = valid ? sc[rt][nt][rg] * SCALE : NEGINF;
      }

  // ---- softmax (rows spread over 16-lane groups) ----
  const float sink = sinks[head];
  float den[2][4];
#pragma unroll
  for (int rt = 0; rt < 2; rt++)
#pragma unroll
    for (int rg = 0; rg < 4; rg++) {
      float m = NEGINF;
#pragma unroll
      for (int nt = 0; nt < 10; nt++) m = fmaxf(m, sc[rt][nt][rg]);
#pragma unroll
      for (int x = 1; x < 16; x <<= 1) m = fmaxf(m, __shfl_xor(m, x, 64));
      m = fmaxf(m, sink);
      float sum = 0.f;
#pragma unroll
      for (int nt = 0; nt < 10; nt++) {
        float p = __expf(sc[rt][nt][rg] - m);
        sc[rt][nt][rg] = p;
        sum += p;
      }
#pragma unroll
      for (int x = 1; x < 16; x <<= 1) sum += __shfl_xor(sum, x, 64);
      den[rt][rg] = sum + __expf(sink - m);
    }

  // ---- PV ----
  f32x4 oacc[2][4];
#pragma unroll
  for (int rt = 0; rt < 2; rt++)
#pragma unroll
    for (int dn = 0; dn < 4; dn++) oacc[rt][dn] = zz;
  u16* slab = &Pslab[w * 32 * 40];
#pragma unroll
  for (int kt = 0; kt < 5; kt++) {
#pragma unroll
    for (int rt = 0; rt < 2; rt++)
#pragma unroll
      for (int j2 = 0; j2 < 2; j2++)
#pragma unroll
        for (int rg = 0; rg < 4; rg++)
          slab[(rt * 16 + lg * 4 + rg) * 40 + j2 * 16 + lr] = f2bf(sc[rt][kt * 2 + j2][rg]);
    asm volatile("s_waitcnt lgkmcnt(0)" ::: "memory");
    __builtin_amdgcn_sched_barrier(0);
    bf16x8 pf0 = *(const bf16x8*)&slab[lr * 40 + lg * 8];
    bf16x8 pf1 = *(const bf16x8*)&slab[(16 + lr) * 40 + lg * 8];
#pragma unroll
    for (int dn = 0; dn < 4; dn++) {
      bf16x8 vf = *(const bf16x8*)&Vt[(dn * 16 + lr) * 168 + kt * 32 + lg * 8];
      oacc[0][dn] = MFMA16(pf0, vf, oacc[0][dn]);
      oacc[1][dn] = MFMA16(pf1, vf, oacc[1][dn]);
    }
  }

  // ---- write normalized output (bf16 for GEMM2) ----
#pragma unroll
  for (int rt = 0; rt < 2; rt++)
#pragma unroll
    for (int dn = 0; dn < 4; dn++)
#pragma unroll
      for (int rg = 0; rg < 4; rg++) {
        int s = s0 + rt * 16 + lg * 4 + rg;
        float val = oacc[rt][dn][rg] / den[rt][rg];
        out[(size_t)s * ATTN_K + head * 64 + dn * 16 + lr] = f2bf(val);
      }
}

extern "C" void kernel_launch(void* const* d_in, const int* in_sizes, int n_in,
                              void* d_out, int out_size, void* d_ws, size_t ws_size,
                              hipStream_t stream) {
  const float* hs = (const float*)d_in[0];
  const int* pos = (const int*)d_in[1];
  const float* wqkv = (const float*)d_in[2];
  const float* bqkv = (const float*)d_in[3];
  const float* wo = (const float*)d_in[4];
  const float* bo = (const float*)d_in[5];
  const float* sinks = (const float*)d_in[6];
  float* out = (float*)d_out;

  char* ws = (char*)d_ws;
  float* qkv = (float*)(ws + 0);                 // 2048*5120*4  = 41,943,040
  u16* hsb = (u16*)(ws + 41943040);              // 2048*2880*2  = 11,796,480
  u16* wqkvT = (u16*)(ws + 53739520);            // 5120*2880*2  = 29,491,200
  u16* woT = (u16*)(ws + 83230720);              // 2944*4096*2  = 24,117,248
  u16* attn = (u16*)(ws + 107347968);            // 2048*4096*2  = 16,777,216
  float2* tab = (float2*)(ws + 124125184);       // 2048*32*8    =    524,288

  k_rope_table<<<256, 256, 0, stream>>>(pos, tab);
  k_convert_hs<<<5760, 256, 0, stream>>>(hs, hsb, 1474560);
  k_transpose<<<dim3(160, 90), 256, 0, stream>>>(wqkv, wqkvT, 2880, 5120, 5120);
  k_transpose<<<dim3(92, 128), 256, 0, stream>>>(wo, woT, 4096, 2880, 2944);
  k_gemm<false><<<dim3(16, 40), 256, 0, stream>>>(hsb, wqkvT, bqkv, qkv, 2880, 5120, 5120);
  k_rope_apply<<<18432, 256, 0, stream>>>(qkv, tab);
  k_attn<<<dim3(64, 8), 512, 0, stream>>>(qkv, sinks, attn);
  k_gemm<true><<<dim3(16, 23), 256, 0, stream>>>(attn, woT, bo, out, 4096, 2880, 2880);
}

// Round 3
// 263.371 us; speedup vs baseline: 1.1317x; 1.0015x over previous
//
#include <hip/hip_runtime.h>

typedef unsigned short u16;
typedef __bf16 bf16x8 __attribute__((ext_vector_type(8)));
typedef float f32x4 __attribute__((ext_vector_type(4)));
typedef unsigned short u16x8 __attribute__((ext_vector_type(8)));

#define QKV_N 5120
#define SEQ 2048
#define ATTN_K 4096
#define KPAD 2944   // 2880 padded to 46*64
#define SCALE 0.125f
#define NEGINF -1e30f

__device__ __forceinline__ u16 f2bf(float f) {
  unsigned int u = __builtin_bit_cast(unsigned int, f);
  u = (u + 0x7FFFu + ((u >> 16) & 1u)) >> 16;
  return (u16)u;
}

#define MFMA16(a, b, c) __builtin_amdgcn_mfma_f32_16x16x32_bf16((a), (b), (c), 0, 0, 0)

// async global->LDS, 16B per lane; LDS dest = wave-uniform base + lane*16
__device__ __forceinline__ void gl_lds16(const u16* g, u16* l) {
  __builtin_amdgcn_global_load_lds(
      (const __attribute__((address_space(1))) unsigned int*)(const void*)g,
      (__attribute__((address_space(3))) unsigned int*)(void*)l, 16, 0, 0);
}

// read a bf16x8 fragment from a swizzled [256][64] bf16 LDS tile
__device__ __forceinline__ bf16x8 lds_frag(const u16* mat, int row, int kh, int lg) {
  int off = row * 128 + ((kh * 64 + lg * 16) ^ ((row & 7) << 4));
  return *(const bf16x8*)((const char*)mat + off);
}

// ---------------- RoPE table: tab[s*32+i] = {cos, sin} ----------------
__global__ __launch_bounds__(256) void k_rope_table(const int* __restrict__ pos,
                                                    float2* __restrict__ tab) {
  int t = blockIdx.x * 256 + threadIdx.x;  // 65536 = 2048*32
  int s = t >> 5, i = t & 31;
  float freq = powf(150000.0f, -(float)i * (1.0f / 32.0f));
  float ang = (float)pos[s] * freq;
  float sv, cv;
  sincosf(ang, &sv, &cv);
  tab[t] = make_float2(cv, sv);
}

// ---------------- f32 -> bf16 convert with K-pad: out [2048][2944] ----------------
__global__ __launch_bounds__(256) void k_convert_pad(const float* __restrict__ in,
                                                     u16* __restrict__ out) {
  int i = blockIdx.x * 256 + threadIdx.x;  // per 4 out elems; 2048*736 total
  int r = i / 736, c4 = i - r * 736;
  if (r >= 2048) return;
  ushort4 o = {0, 0, 0, 0};
  if (c4 < 720) {
    float4 v = *(const float4*)(in + (size_t)r * 2880 + c4 * 4);
    o.x = f2bf(v.x); o.y = f2bf(v.y); o.z = f2bf(v.z); o.w = f2bf(v.w);
  }
  ((ushort4*)out)[(size_t)r * 736 + c4] = o;
}

// ------ transpose+convert: in f32 [Kin][Nd] -> out bf16 [Npad][Kout], zero-padded ------
__global__ __launch_bounds__(256) void k_transpose(const float* __restrict__ in,
                                                   u16* __restrict__ out,
                                                   int Kin, int Kout, int Nd, int Npad) {
  __shared__ float tile[32][33];
  int n0 = blockIdx.x * 32, k0 = blockIdx.y * 32;
  int c = threadIdx.x & 31, r0 = threadIdx.x >> 5;
#pragma unroll
  for (int j = 0; j < 4; j++) {
    int r = r0 + j * 8;
    float v = 0.f;
    if (n0 + c < Nd && k0 + r < Kin) v = in[(size_t)(k0 + r) * Nd + n0 + c];
    tile[r][c] = v;
  }
  __syncthreads();
#pragma unroll
  for (int j = 0; j < 4; j++) {
    int rr = r0 + j * 8;  // local n
    int n = n0 + rr;
    if (n < Npad) out[(size_t)n * Kout + k0 + c] = f2bf(tile[c][rr]);
  }
}

// ======== GEMM1: 256x256 tile, BK=64, ring-dbuf deep pipeline, fused bias+RoPE ========
// A [2048][2944] bf16, B [5120][2944] bf16 (B^T), C = qkv f32 [2048][5120].
// 512 thr = 8 waves (2M x 4N); per-wave C = 128x64 (8x4 frags). LDS 128 KiB.
__global__ __launch_bounds__(512, 1) void k_gemm1(const u16* __restrict__ Ag,
                                                  const u16* __restrict__ Bg,
                                                  const float* __restrict__ bias,
                                                  const float2* __restrict__ tab,
                                                  float* __restrict__ C) {
  __shared__ u16 ldsbuf[2][32768];  // [buf][A 16384 u16 | B 16384 u16]
  const int tid = threadIdx.x;
  const int lane = tid & 63, wave = tid >> 6;
  const int wm = wave >> 2, wn = wave & 3;
  const int lr = lane & 15, lg = lane >> 4;
  // XCD swizzle: nwg=160 (8 m-tiles x 20 n-tiles), 20 contiguous per XCD (one A panel)
  int bid = blockIdx.x;
  int sb = (bid & 7) * 20 + (bid >> 3);
  const int m0 = (sb / 20) * 256, n0 = (sb % 20) * 256;

  f32x4 acc[8][4] = {};

  // ---- prologue: stage tile 0 into buf0 ----
#pragma unroll
  for (int r = 0; r < 4; r++) {
    const int row = r * 64 + wave * 8 + (lane >> 3);
    const int sc = ((lane & 7) ^ (row & 7)) << 3;  // pre-swizzled source chunk
    gl_lds16(Ag + (size_t)(m0 + row) * KPAD + sc, &ldsbuf[0][0] + r * 4096 + wave * 512);
    gl_lds16(Bg + (size_t)(n0 + row) * KPAD + sc, &ldsbuf[0][16384] + r * 4096 + wave * 512);
  }
  asm volatile("s_waitcnt vmcnt(0)" ::: "memory");
  __builtin_amdgcn_s_barrier();

  for (int t = 0; t < 46; t++) {
    const int b = t & 1;
    const u16* La = &ldsbuf[b][0];
    const u16* Lb = &ldsbuf[b][16384];
    bf16x8 Bf[4][2];
    // ---- sub-phase 0: read all B frags + A quad 0; issue next-tile stage ----
#pragma unroll
    for (int nf = 0; nf < 4; nf++)
#pragma unroll
      for (int kh = 0; kh < 2; kh++)
        Bf[nf][kh] = lds_frag(Lb, wn * 64 + nf * 16 + lr, kh, lg);
    {
      bf16x8 Af[2][2];
#pragma unroll
      for (int mi = 0; mi < 2; mi++)
#pragma unroll
        for (int kh = 0; kh < 2; kh++)
          Af[mi][kh] = lds_frag(La, wm * 128 + mi * 16 + lr, kh, lg);
      if (t < 45) {
        const int kt = (t + 1) * 64;
        u16* Ld = &ldsbuf[b ^ 1][0];
#pragma unroll
        for (int r = 0; r < 4; r++) {
          const int row = r * 64 + wave * 8 + (lane >> 3);
          const int sc = ((lane & 7) ^ (row & 7)) << 3;
          gl_lds16(Ag + (size_t)(m0 + row) * KPAD + kt + sc, Ld + r * 4096 + wave * 512);
          gl_lds16(Bg + (size_t)(n0 + row) * KPAD + kt + sc, Ld + 16384 + r * 4096 + wave * 512);
        }
      }
      __builtin_amdgcn_s_barrier();
      __builtin_amdgcn_s_setprio(1);
#pragma unroll
      for (int mi = 0; mi < 2; mi++)
#pragma unroll
        for (int nf = 0; nf < 4; nf++)
#pragma unroll
          for (int kh = 0; kh < 2; kh++)
            acc[mi][nf] = MFMA16(Af[mi][kh], Bf[nf][kh], acc[mi][nf]);
      __builtin_amdgcn_s_setprio(0);
      __builtin_amdgcn_s_barrier();
    }
    // ---- sub-phases 1..3: A quads 1..3 ----
#pragma unroll
    for (int q = 1; q < 4; q++) {
      bf16x8 Af[2][2];
#pragma unroll
      for (int mi = 0; mi < 2; mi++)
#pragma unroll
        for (int kh = 0; kh < 2; kh++)
          Af[mi][kh] = lds_frag(La, wm * 128 + (q * 2 + mi) * 16 + lr, kh, lg);
      __builtin_amdgcn_s_barrier();
      __builtin_amdgcn_s_setprio(1);
#pragma unroll
      for (int mi = 0; mi < 2; mi++)
#pragma unroll
        for (int nf = 0; nf < 4; nf++)
#pragma unroll
          for (int kh = 0; kh < 2; kh++)
            acc[q * 2 + mi][nf] = MFMA16(Af[mi][kh], Bf[nf][kh], acc[q * 2 + mi][nf]);
      __builtin_amdgcn_s_setprio(0);
      __builtin_amdgcn_s_barrier();
    }
    // ---- tile boundary: certify next tile staged (issued ~4 sub-phases ago) ----
    asm volatile("s_waitcnt vmcnt(0)" ::: "memory");
    __builtin_amdgcn_s_barrier();
  }

  // ---- epilogue: bias (+ RoPE for Q/K region), f32 store ----
  const bool rope = (n0 < 4608);  // tiles y<18 are Q+K heads; y>=18 is V
  if (rope) {
#pragma unroll
    for (int mf = 0; mf < 8; mf++)
#pragma unroll
      for (int nf = 0; nf < 2; nf++) {
        int col1 = n0 + wn * 64 + nf * 16 + lr;
        int col2 = col1 + 32;
        float b1 = bias[col1], b2 = bias[col2];
#pragma unroll
        for (int rg = 0; rg < 4; rg++) {
          int row = m0 + wm * 128 + mf * 16 + lg * 4 + rg;
          float2 cs = tab[(size_t)row * 32 + nf * 16 + lr];
          float x1 = acc[mf][nf][rg] + b1;
          float x2 = acc[mf][nf + 2][rg] + b2;
          C[(size_t)row * QKV_N + col1] = x1 * cs.x - x2 * cs.y;
          C[(size_t)row * QKV_N + col2] = x2 * cs.x + x1 * cs.y;
        }
      }
  } else {
#pragma unroll
    for (int mf = 0; mf < 8; mf++)
#pragma unroll
      for (int nf = 0; nf < 4; nf++) {
        int col = n0 + wn * 64 + nf * 16 + lr;
        float bv = bias[col];
#pragma unroll
        for (int rg = 0; rg < 4; rg++) {
          int row = m0 + wm * 128 + mf * 16 + lg * 4 + rg;
          C[(size_t)row * QKV_N + col] = acc[mf][nf][rg] + bv;
        }
      }
  }
}

// ---------------- GEMM2 (m97 structure): C[m][n] = sum_k A[m][k]*B[n][k] + bias[n] ----
// 128x128 tile, BK=32, 4 waves, global_load_lds, linear LDS, XCD-swizzled 1D grid.
__global__ __launch_bounds__(256, 2) void k_gemm2(const u16* __restrict__ A,
                                                  const u16* __restrict__ B,
                                                  const float* __restrict__ bias,
                                                  float* __restrict__ C,
                                                  int K, int Nlog, int ldc,
                                                  int gy, int cpx) {
  __shared__ u16 Alds[128 * 32];
  __shared__ u16 Blds[128 * 32];
  const int tid = threadIdx.x;
  const int lane = tid & 63, wave = tid >> 6;
  const int wm = wave >> 1, wn = wave & 1;
  int bid = blockIdx.x;
  int sb = (bid & 7) * cpx + (bid >> 3);
  const int m0 = (sb / gy) * 128, n0 = (sb % gy) * 128;
  const int lr = lane & 15, lg = lane >> 4;

  f32x4 acc[4][4];
  f32x4 zz = {0.f, 0.f, 0.f, 0.f};
#pragma unroll
  for (int a = 0; a < 4; a++)
#pragma unroll
    for (int b = 0; b < 4; b++) acc[a][b] = zz;

  const int srow = wave * 16 + (lane >> 2);
  const int schk = (lane & 3) * 8;
  const u16* gA0 = A + (size_t)(m0 + srow) * K + schk;
  const u16* gA1 = A + (size_t)(m0 + srow + 64) * K + schk;
  const u16* gB0 = B + (size_t)(n0 + srow) * K + schk;
  const u16* gB1 = B + (size_t)(n0 + srow + 64) * K + schk;
  u16* lA0 = &Alds[wave * 512];
  u16* lA1 = &Alds[wave * 512 + 2048];
  u16* lB0 = &Blds[wave * 512];
  u16* lB1 = &Blds[wave * 512 + 2048];

  const u16* pa = &Alds[(wm * 64 + lr) * 32 + lg * 8];
  const u16* pb = &Blds[(wn * 64 + lr) * 32 + lg * 8];

  for (int kt = 0; kt < K; kt += 32) {
    gl_lds16(gA0 + kt, lA0);
    gl_lds16(gA1 + kt, lA1);
    gl_lds16(gB0 + kt, lB0);
    gl_lds16(gB1 + kt, lB1);
    __syncthreads();

    bf16x8 af[4], bfm[4];
#pragma unroll
    for (int mi = 0; mi < 4; mi++) af[mi] = *(const bf16x8*)(pa + mi * 512);
#pragma unroll
    for (int ni = 0; ni < 4; ni++) bfm[ni] = *(const bf16x8*)(pb + ni * 512);

#pragma unroll
    for (int mi = 0; mi < 4; mi++)
#pragma unroll
      for (int ni = 0; ni < 4; ni++)
        acc[mi][ni] = MFMA16(af[mi], bfm[ni], acc[mi][ni]);
    __syncthreads();
  }

#pragma unroll
  for (int mi = 0; mi < 4; mi++)
#pragma unroll
    for (int ni = 0; ni < 4; ni++) {
      int row = m0 + wm * 64 + mi * 16 + lg * 4;
      int col = n0 + wn * 64 + ni * 16 + lr;
      if (col < Nlog) {
        float bv = bias[col];
#pragma unroll
        for (int rg = 0; rg < 4; rg++)
          C[(size_t)(row + rg) * ldc + col] = acc[mi][ni][rg] + bv;
      }
    }
}

// ---------------- sliding-window attention with sinks ----------------
__global__ __launch_bounds__(512, 2) void k_attn(const float* __restrict__ qkv,
                                                 const float* __restrict__ sinks,
                                                 u16* __restrict__ out) {
  __shared__ u16 Klds[160 * 64];
  __shared__ u16 Vt[64 * 168];
  __shared__ u16 Pslab[8 * 32 * 40];
  const int hk = blockIdx.y;
  const int s0 = blockIdx.x * 32;
  const int kb = s0 - 127;
  const int tid = threadIdx.x;
  const int lane = tid & 63, w = tid >> 6;
  const int lr = lane & 15, lg = lane >> 4;

  for (int ch = tid; ch < 160 * 8; ch += 512) {
    int key = ch >> 3, c = ch & 7;
    int kidx = kb + key;
    u16x8 val = {0, 0, 0, 0, 0, 0, 0, 0};
    if (kidx >= 0 && kidx < SEQ) {
      const float4* g = (const float4*)(qkv + (size_t)kidx * QKV_N + 4096 + hk * 64 + c * 8);
      float4 f0 = g[0], f1 = g[1];
      val[0] = f2bf(f0.x); val[1] = f2bf(f0.y); val[2] = f2bf(f0.z); val[3] = f2bf(f0.w);
      val[4] = f2bf(f1.x); val[5] = f2bf(f1.y); val[6] = f2bf(f1.z); val[7] = f2bf(f1.w);
    }
    int off = (key * 128 + c * 16) ^ ((key & 7) << 4);
    *(u16x8*)((char*)Klds + off) = val;
  }
  for (int e4 = tid; e4 < 160 * 16; e4 += 512) {
    int key = e4 >> 4, d0 = (e4 & 15) * 4;
    int kidx = kb + key;
    float4 v = make_float4(0.f, 0.f, 0.f, 0.f);
    if (kidx >= 0 && kidx < SEQ)
      v = *(const float4*)(qkv + (size_t)kidx * QKV_N + 4608 + hk * 64 + d0);
    Vt[(d0 + 0) * 168 + key] = f2bf(v.x);
    Vt[(d0 + 1) * 168 + key] = f2bf(v.y);
    Vt[(d0 + 2) * 168 + key] = f2bf(v.z);
    Vt[(d0 + 3) * 168 + key] = f2bf(v.w);
  }

  const int head = hk * 8 + w;
  bf16x8 qf[2][2];
#pragma unroll
  for (int rt = 0; rt < 2; rt++)
#pragma unroll
    for (int ks = 0; ks < 2; ks++) {
      const float* g = qkv + (size_t)(s0 + rt * 16 + lr) * QKV_N + head * 64 + ks * 32 + lg * 8;
      float4 f0 = *(const float4*)g, f1 = *(const float4*)(g + 4);
      u16x8 u;
      u[0] = f2bf(f0.x); u[1] = f2bf(f0.y); u[2] = f2bf(f0.z); u[3] = f2bf(f0.w);
      u[4] = f2bf(f1.x); u[5] = f2bf(f1.y); u[6] = f2bf(f1.z); u[7] = f2bf(f1.w);
      qf[rt][ks] = __builtin_bit_cast(bf16x8, u);
    }
  __syncthreads();

  f32x4 sc[2][10];
  f32x4 zz = {0.f, 0.f, 0.f, 0.f};
#pragma unroll
  for (int rt = 0; rt < 2; rt++)
#pragma unroll
    for (int nt = 0; nt < 10; nt++) sc[rt][nt] = zz;
#pragma unroll
  for (int nt = 0; nt < 10; nt++) {
    int key = nt * 16 + lr;
#pragma unroll
    for (int ks = 0; ks < 2; ks++) {
      int off = (key * 128 + ks * 64 + lg * 16) ^ ((key & 7) << 4);
      bf16x8 kf = *(const bf16x8*)((const char*)Klds + off);
      sc[0][nt] = MFMA16(qf[0][ks], kf, sc[0][nt]);
      sc[1][nt] = MFMA16(qf[1][ks], kf, sc[1][nt]);
    }
  }

#pragma unroll
  for (int rt = 0; rt < 2; rt++)
#pragma unroll
    for (int nt = 0; nt < 10; nt++)
#pragma unroll
      for (int rg = 0; rg < 4; rg++) {
        int qq = rt * 16 + lg * 4 + rg;
        int j = nt * 16 + lr;
        bool valid = (j >= qq) && (j <= qq + 127) && ((kb + j) >= 0);
        sc[rt][nt][rg] = valid ? sc[rt][nt][rg] * SCALE : NEGINF;
      }

  const float sink = sinks[head];
  float den[2][4];
#pragma unroll
  for (int rt = 0; rt < 2; rt++)
#pragma unroll
    for (int rg = 0; rg < 4; rg++) {
      float m = NEGINF;
#pragma unroll
      for (int nt = 0; nt < 10; nt++) m = fmaxf(m, sc[rt][nt][rg]);
#pragma unroll
      for (int x = 1; x < 16; x <<= 1) m = fmaxf(m, __shfl_xor(m, x, 64));
      m = fmaxf(m, sink);
      float sum = 0.f;
#pragma unroll
      for (int nt = 0; nt < 10; nt++) {
        float p = __expf(sc[rt][nt][rg] - m);
        sc[rt][nt][rg] = p;
        sum += p;
      }
#pragma unroll
      for (int x = 1; x < 16; x <<= 1) sum += __shfl_xor(sum, x, 64);
      den[rt][rg] = sum + __expf(sink - m);
    }

  f32x4 oacc[2][4];
#pragma unroll
  for (int rt = 0; rt < 2; rt++)
#pragma unroll
    for (int dn = 0; dn < 4; dn++) oacc[rt][dn] = zz;
  u16* slab = &Pslab[w * 32 * 40];
#pragma unroll
  for (int kt = 0; kt < 5; kt++) {
#pragma unroll
    for (int rt = 0; rt < 2; rt++)
#pragma unroll
      for (int j2 = 0; j2 < 2; j2++)
#pragma unroll
        for (int rg = 0; rg < 4; rg++)
          slab[(rt * 16 + lg * 4 + rg) * 40 + j2 * 16 + lr] = f2bf(sc[rt][kt * 2 + j2][rg]);
    asm volatile("s_waitcnt lgkmcnt(0)" ::: "memory");
    __builtin_amdgcn_sched_barrier(0);
    bf16x8 pf0 = *(const bf16x8*)&slab[lr * 40 + lg * 8];
    bf16x8 pf1 = *(const bf16x8*)&slab[(16 + lr) * 40 + lg * 8];
#pragma unroll
    for (int dn = 0; dn < 4; dn++) {
      bf16x8 vf = *(const bf16x8*)&Vt[(dn * 16 + lr) * 168 + kt * 32 + lg * 8];
      oacc[0][dn] = MFMA16(pf0, vf, oacc[0][dn]);
      oacc[1][dn] = MFMA16(pf1, vf, oacc[1][dn]);
    }
  }

#pragma unroll
  for (int rt = 0; rt < 2; rt++)
#pragma unroll
    for (int dn = 0; dn < 4; dn++)
#pragma unroll
      for (int rg = 0; rg < 4; rg++) {
        int s = s0 + rt * 16 + lg * 4 + rg;
        float val = oacc[rt][dn][rg] / den[rt][rg];
        out[(size_t)s * ATTN_K + head * 64 + dn * 16 + lr] = f2bf(val);
      }
}

extern "C" void kernel_launch(void* const* d_in, const int* in_sizes, int n_in,
                              void* d_out, int out_size, void* d_ws, size_t ws_size,
                              hipStream_t stream) {
  const float* hs = (const float*)d_in[0];
  const int* pos = (const int*)d_in[1];
  const float* wqkv = (const float*)d_in[2];
  const float* bqkv = (const float*)d_in[3];
  const float* wo = (const float*)d_in[4];
  const float* bo = (const float*)d_in[5];
  const float* sinks = (const float*)d_in[6];
  float* out = (float*)d_out;

  char* ws = (char*)d_ws;
  float* qkv = (float*)(ws + 0);            // 2048*5120*4 = 41,943,040
  u16* hsb = (u16*)(ws + 41943040);         // 2048*2944*2 = 12,058,624
  u16* wqkvT = (u16*)(ws + 54001664);       // 5120*2944*2 = 30,146,560 -> ends 84,148,224
  u16* attnb = (u16*)(ws + 41943040);       // 2048*4096*2 = 16,777,216 (aliases dead hsb/wqkvT)
  u16* woT = (u16*)(ws + 84148224);         // 2944*4096*2 = 24,117,248 -> ends 108,265,472
  float2* tab = (float2*)(ws + 108265472);  // 2048*32*8   = 524,288

  k_rope_table<<<256, 256, 0, stream>>>(pos, tab);
  k_convert_pad<<<5888, 256, 0, stream>>>(hs, hsb);
  k_transpose<<<dim3(160, 92), 256, 0, stream>>>(wqkv, wqkvT, 2880, KPAD, 5120, 5120);
  k_transpose<<<dim3(92, 128), 256, 0, stream>>>(wo, woT, 4096, 4096, 2880, 2944);
  k_gemm1<<<160, 512, 0, stream>>>(hsb, wqkvT, bqkv, tab, qkv);
  k_attn<<<dim3(64, 8), 512, 0, stream>>>(qkv, sinks, attnb);
  k_gemm2<<<368, 256, 0, stream>>>(attnb, woT, bo, out, 4096, 2880, 2880, 23, 46);
}

// Round 4
// 221.398 us; speedup vs baseline: 1.3462x; 1.1896x over previous
//
#include <hip/hip_runtime.h>

typedef unsigned short u16;
typedef __bf16 bf16x8 __attribute__((ext_vector_type(8)));
typedef float f32x4 __attribute__((ext_vector_type(4)));
typedef unsigned short u16x8 __attribute__((ext_vector_type(8)));

#define QKV_N 5120
#define SEQ 2048
#define ATTN_K 4096
#define KPAD 2944   // 2880 padded to 46*64
#define SCALE 0.125f
#define NEGINF -1e30f

__device__ __forceinline__ u16 f2bf(float f) {
  unsigned int u = __builtin_bit_cast(unsigned int, f);
  u = (u + 0x7FFFu + ((u >> 16) & 1u)) >> 16;
  return (u16)u;
}

#define MFMA16(a, b, c) __builtin_amdgcn_mfma_f32_16x16x32_bf16((a), (b), (c), 0, 0, 0)

// async global->LDS, 16B per lane; LDS dest = wave-uniform base + lane*16
__device__ __forceinline__ void gl_lds16(const u16* g, u16* l) {
  __builtin_amdgcn_global_load_lds(
      (const __attribute__((address_space(1))) unsigned int*)(const void*)g,
      (__attribute__((address_space(3))) unsigned int*)(void*)l, 16, 0, 0);
}

// read a bf16x8 fragment from a swizzled [rows][64] bf16 LDS tile (128 B/row)
__device__ __forceinline__ bf16x8 lds_frag(const u16* mat, int row, int kh, int lg) {
  int off = row * 128 + ((kh * 64 + lg * 16) ^ ((row & 7) << 4));
  return *(const bf16x8*)((const char*)mat + off);
}

// ---------------- RoPE table: tab[s*32+i] = {cos, sin} ----------------
__global__ __launch_bounds__(256) void k_rope_table(const int* __restrict__ pos,
                                                    float2* __restrict__ tab) {
  int t = blockIdx.x * 256 + threadIdx.x;  // 65536 = 2048*32
  int s = t >> 5, i = t & 31;
  float freq = powf(150000.0f, -(float)i * (1.0f / 32.0f));
  float ang = (float)pos[s] * freq;
  float sv, cv;
  sincosf(ang, &sv, &cv);
  tab[t] = make_float2(cv, sv);
}

// ---------------- f32 -> bf16 convert with K-pad: out [2048][2944] ----------------
__global__ __launch_bounds__(256) void k_convert_pad(const float* __restrict__ in,
                                                     u16* __restrict__ out) {
  int i = blockIdx.x * 256 + threadIdx.x;  // per 4 out elems; 2048*736 total
  int r = i / 736, c4 = i - r * 736;
  if (r >= 2048) return;
  ushort4 o = {0, 0, 0, 0};
  if (c4 < 720) {
    float4 v = *(const float4*)(in + (size_t)r * 2880 + c4 * 4);
    o.x = f2bf(v.x); o.y = f2bf(v.y); o.z = f2bf(v.z); o.w = f2bf(v.w);
  }
  ((ushort4*)out)[(size_t)r * 736 + c4] = o;
}

// ------ transpose+convert: in f32 [Kin][Nd] -> out bf16 [Npad][Kout], zero-padded ------
__global__ __launch_bounds__(256) void k_transpose(const float* __restrict__ in,
                                                   u16* __restrict__ out,
                                                   int Kin, int Kout, int Nd, int Npad) {
  __shared__ float tile[32][33];
  int n0 = blockIdx.x * 32, k0 = blockIdx.y * 32;
  int c = threadIdx.x & 31, r0 = threadIdx.x >> 5;
#pragma unroll
  for (int j = 0; j < 4; j++) {
    int r = r0 + j * 8;
    float v = 0.f;
    if (n0 + c < Nd && k0 + r < Kin) v = in[(size_t)(k0 + r) * Nd + n0 + c];
    tile[r][c] = v;
  }
  __syncthreads();
#pragma unroll
  for (int j = 0; j < 4; j++) {
    int rr = r0 + j * 8;  // local n
    int n = n0 + rr;
    if (n < Npad) out[(size_t)n * Kout + k0 + c] = f2bf(tile[c][rr]);
  }
}

// ======== GEMM1: 256x256, BK=64, 2-tile ring + COUNTED vmcnt, fused bias+RoPE ========
// A [2048][2944] bf16, B [5120][2944] bf16 (B^T), out qkv bf16 [2048][5120].
__global__ __launch_bounds__(512, 1) void k_gemm1(const u16* __restrict__ Ag,
                                                  const u16* __restrict__ Bg,
                                                  const float* __restrict__ bias,
                                                  const float2* __restrict__ tab,
                                                  u16* __restrict__ C) {
  __shared__ u16 ldsbuf[2][32768];  // [buf][A 16384 u16 | B 16384 u16]
  const int tid = threadIdx.x;
  const int lane = tid & 63, wave = tid >> 6;
  const int wm = wave >> 2, wn = wave & 3;
  const int lr = lane & 15, lg = lane >> 4;
  int bid = blockIdx.x;
  int sb = (bid & 7) * 20 + (bid >> 3);  // 160 = 8 XCD x 20
  const int m0 = (sb / 20) * 256, n0 = (sb % 20) * 256;

  f32x4 acc[8][4] = {};

  const int srow = wave * 8 + (lane >> 3);            // within 64-row round
  const int sc = ((lane & 7) ^ (lane >> 3)) << 3;     // pre-swizzled chunk (elems)
  const u16* gA = Ag + (size_t)(m0 + srow) * KPAD + sc;
  const u16* gB = Bg + (size_t)(n0 + srow) * KPAD + sc;

#define G1_STAGE(kt, b)                                                          \
  {                                                                              \
    u16* Ab = &ldsbuf[b][0];                                                     \
    u16* Bb = &ldsbuf[b][16384];                                                 \
    _Pragma("unroll") for (int r = 0; r < 4; r++) {                              \
      gl_lds16(gA + (size_t)(r * 64) * KPAD + (kt), Ab + (r * 64 + wave * 8) * 64); \
      gl_lds16(gB + (size_t)(r * 64) * KPAD + (kt), Bb + (r * 64 + wave * 8) * 64); \
    }                                                                            \
  }

  // prologue: T0 -> buf0, T1 -> buf1; certify T0 (8 newest stay in flight)
  G1_STAGE(0, 0)
  G1_STAGE(64, 1)
  asm volatile("s_waitcnt vmcnt(8)" ::: "memory");
  __builtin_amdgcn_s_barrier();

  for (int t = 0; t < 46; t++) {
    const int b = t & 1;
    const u16* La = &ldsbuf[b][0];
    const u16* Lb = &ldsbuf[b][16384];
    bf16x8 Bf[4][2];
#pragma unroll
    for (int nf = 0; nf < 4; nf++)
#pragma unroll
      for (int kh = 0; kh < 2; kh++)
        Bf[nf][kh] = lds_frag(Lb, wn * 64 + nf * 16 + lr, kh, lg);
#pragma unroll
    for (int q = 0; q < 4; q++) {
      bf16x8 Af[2][2];
#pragma unroll
      for (int mi = 0; mi < 2; mi++)
#pragma unroll
        for (int kh = 0; kh < 2; kh++)
          Af[mi][kh] = lds_frag(La, wm * 128 + (q * 2 + mi) * 16 + lr, kh, lg);
      __builtin_amdgcn_s_barrier();
      __builtin_amdgcn_s_setprio(1);
#pragma unroll
      for (int mi = 0; mi < 2; mi++)
#pragma unroll
        for (int nf = 0; nf < 4; nf++)
#pragma unroll
          for (int kh = 0; kh < 2; kh++)
            acc[q * 2 + mi][nf] = MFMA16(Af[mi][kh], Bf[nf][kh], acc[q * 2 + mi][nf]);
      __builtin_amdgcn_s_setprio(0);
      __builtin_amdgcn_s_barrier();
    }
    // all waves done reading buf[b] (lgkm0 before MFMA + barrier) -> restage it
    if (t <= 43) {
      G1_STAGE((t + 2) * 64, b)
      asm volatile("s_waitcnt vmcnt(8)" ::: "memory");  // t+1 resident; t+2 in flight
    } else {
      asm volatile("s_waitcnt vmcnt(0)" ::: "memory");
    }
    __builtin_amdgcn_s_barrier();
  }
#undef G1_STAGE

  // ---- epilogue: bias (+ RoPE for Q/K cols), bf16 store ----
  const bool rope = (n0 < 4608);
  if (rope) {
#pragma unroll
    for (int mf = 0; mf < 8; mf++)
#pragma unroll
      for (int nf = 0; nf < 2; nf++) {
        int col1 = n0 + wn * 64 + nf * 16 + lr;
        int col2 = col1 + 32;
        float b1 = bias[col1], b2 = bias[col2];
#pragma unroll
        for (int rg = 0; rg < 4; rg++) {
          int row = m0 + wm * 128 + mf * 16 + lg * 4 + rg;
          float2 cs = tab[(size_t)row * 32 + nf * 16 + lr];
          float x1 = acc[mf][nf][rg] + b1;
          float x2 = acc[mf][nf + 2][rg] + b2;
          C[(size_t)row * QKV_N + col1] = f2bf(x1 * cs.x - x2 * cs.y);
          C[(size_t)row * QKV_N + col2] = f2bf(x2 * cs.x + x1 * cs.y);
        }
      }
  } else {
#pragma unroll
    for (int mf = 0; mf < 8; mf++)
#pragma unroll
      for (int nf = 0; nf < 4; nf++) {
        int col = n0 + wn * 64 + nf * 16 + lr;
        float bv = bias[col];
#pragma unroll
        for (int rg = 0; rg < 4; rg++) {
          int row = m0 + wm * 128 + mf * 16 + lg * 4 + rg;
          C[(size_t)row * QKV_N + col] = f2bf(acc[mf][nf][rg] + bv);
        }
      }
  }
}

// ======== GEMM2: 128x128, BK=64, 2-tile ring + COUNTED vmcnt, 2 blocks/CU ========
// A = attn bf16 [2048][4096], B = woT bf16 [2944][4096], C f32 [2048][2880].
__global__ __launch_bounds__(256, 2) void k_gemm2(const u16* __restrict__ Ag,
                                                  const u16* __restrict__ Bg,
                                                  const float* __restrict__ bias,
                                                  float* __restrict__ C) {
  __shared__ u16 ldsbuf[2][16384];  // [buf][A 8192 | B 8192]
  const int tid = threadIdx.x;
  const int lane = tid & 63, wave = tid >> 6;
  const int wm = wave >> 1, wn = wave & 1;
  const int lr = lane & 15, lg = lane >> 4;
  int bid = blockIdx.x;
  int sb = (bid & 7) * 46 + (bid >> 3);  // 368 = 8 XCD x 46
  const int m0 = (sb / 23) * 128, n0 = (sb % 23) * 128;

  f32x4 acc[4][4] = {};

  const int srow = wave * 8 + (lane >> 3);         // within 32-row round
  const int sc = ((lane & 7) ^ (lane >> 3)) << 3;  // pre-swizzled chunk
  const u16* gA = Ag + (size_t)(m0 + srow) * ATTN_K + sc;
  const u16* gB = Bg + (size_t)(n0 + srow) * ATTN_K + sc;

#define G2_STAGE(kt, b)                                                          \
  {                                                                              \
    u16* Ab = &ldsbuf[b][0];                                                     \
    u16* Bb = &ldsbuf[b][8192];                                                  \
    _Pragma("unroll") for (int r = 0; r < 4; r++) {                              \
      gl_lds16(gA + (size_t)(r * 32) * ATTN_K + (kt), Ab + (r * 32 + wave * 8) * 64); \
      gl_lds16(gB + (size_t)(r * 32) * ATTN_K + (kt), Bb + (r * 32 + wave * 8) * 64); \
    }                                                                            \
  }

  G2_STAGE(0, 0)
  G2_STAGE(64, 1)
  asm volatile("s_waitcnt vmcnt(8)" ::: "memory");
  __builtin_amdgcn_s_barrier();

  for (int t = 0; t < 64; t++) {
    const int b = t & 1;
    const u16* La = &ldsbuf[b][0];
    const u16* Lb = &ldsbuf[b][8192];
    bf16x8 Bf[4][2];
#pragma unroll
    for (int nf = 0; nf < 4; nf++)
#pragma unroll
      for (int kh = 0; kh < 2; kh++)
        Bf[nf][kh] = lds_frag(Lb, wn * 64 + nf * 16 + lr, kh, lg);
#pragma unroll
    for (int q = 0; q < 2; q++) {
      bf16x8 Af[2][2];
#pragma unroll
      for (int mi = 0; mi < 2; mi++)
#pragma unroll
        for (int kh = 0; kh < 2; kh++)
          Af[mi][kh] = lds_frag(La, wm * 64 + (q * 2 + mi) * 16 + lr, kh, lg);
      __builtin_amdgcn_s_barrier();
      __builtin_amdgcn_s_setprio(1);
#pragma unroll
      for (int mi = 0; mi < 2; mi++)
#pragma unroll
        for (int nf = 0; nf < 4; nf++)
#pragma unroll
          for (int kh = 0; kh < 2; kh++)
            acc[q * 2 + mi][nf] = MFMA16(Af[mi][kh], Bf[nf][kh], acc[q * 2 + mi][nf]);
      __builtin_amdgcn_s_setprio(0);
      __builtin_amdgcn_s_barrier();
    }
    if (t <= 61) {
      G2_STAGE((t + 2) * 64, b)
      asm volatile("s_waitcnt vmcnt(8)" ::: "memory");
    } else {
      asm volatile("s_waitcnt vmcnt(0)" ::: "memory");
    }
    __builtin_amdgcn_s_barrier();
  }
#undef G2_STAGE

#pragma unroll
  for (int mi = 0; mi < 4; mi++)
#pragma unroll
    for (int ni = 0; ni < 4; ni++) {
      int row = m0 + wm * 64 + mi * 16 + lg * 4;
      int col = n0 + wn * 64 + ni * 16 + lr;
      if (col < 2880) {
        float bv = bias[col];
#pragma unroll
        for (int rg = 0; rg < 4; rg++)
          C[(size_t)(row + rg) * 2880 + col] = acc[mi][ni][rg] + bv;
      }
    }
}

// ---------------- sliding-window attention with sinks (bf16 qkv input) ----------------
__global__ __launch_bounds__(512, 2) void k_attn(const u16* __restrict__ qkv,
                                                 const float* __restrict__ sinks,
                                                 u16* __restrict__ out) {
  __shared__ u16 Klds[160 * 64];
  __shared__ u16 Vt[64 * 168];
  __shared__ u16 Pslab[8 * 32 * 40];
  const int hk = blockIdx.y;
  const int s0 = blockIdx.x * 32;
  const int kb = s0 - 127;
  const int tid = threadIdx.x;
  const int lane = tid & 63, w = tid >> 6;
  const int lr = lane & 15, lg = lane >> 4;

  for (int ch = tid; ch < 160 * 8; ch += 512) {
    int key = ch >> 3, c = ch & 7;
    int kidx = kb + key;
    u16x8 val = {0, 0, 0, 0, 0, 0, 0, 0};
    if (kidx >= 0 && kidx < SEQ)
      val = *(const u16x8*)(qkv + (size_t)kidx * QKV_N + 4096 + hk * 64 + c * 8);
    int off = (key * 128 + c * 16) ^ ((key & 7) << 4);
    *(u16x8*)((char*)Klds + off) = val;
  }
  for (int e4 = tid; e4 < 160 * 16; e4 += 512) {
    int key = e4 >> 4, d0 = (e4 & 15) * 4;
    int kidx = kb + key;
    ushort4 v = {0, 0, 0, 0};
    if (kidx >= 0 && kidx < SEQ)
      v = *(const ushort4*)(qkv + (size_t)kidx * QKV_N + 4608 + hk * 64 + d0);
    Vt[(d0 + 0) * 168 + key] = v.x;
    Vt[(d0 + 1) * 168 + key] = v.y;
    Vt[(d0 + 2) * 168 + key] = v.z;
    Vt[(d0 + 3) * 168 + key] = v.w;
  }

  const int head = hk * 8 + w;
  bf16x8 qf[2][2];
#pragma unroll
  for (int rt = 0; rt < 2; rt++)
#pragma unroll
    for (int ks = 0; ks < 2; ks++)
      qf[rt][ks] = *(const bf16x8*)(qkv + (size_t)(s0 + rt * 16 + lr) * QKV_N +
                                    head * 64 + ks * 32 + lg * 8);
  __syncthreads();

  f32x4 sc[2][10];
  f32x4 zz = {0.f, 0.f, 0.f, 0.f};
#pragma unroll
  for (int rt = 0; rt < 2; rt++)
#pragma unroll
    for (int nt = 0; nt < 10; nt++) sc[rt][nt] = zz;
#pragma unroll
  for (int nt = 0; nt < 10; nt++) {
    int key = nt * 16 + lr;
#pragma unroll
    for (int ks = 0; ks < 2; ks++) {
      int off = (key * 128 + ks * 64 + lg * 16) ^ ((key & 7) << 4);
      bf16x8 kf = *(const bf16x8*)((const char*)Klds + off);
      sc[0][nt] = MFMA16(qf[0][ks], kf, sc[0][nt]);
      sc[1][nt] = MFMA16(qf[1][ks], kf, sc[1][nt]);
    }
  }

#pragma unroll
  for (int rt = 0; rt < 2; rt++)
#pragma unroll
    for (int nt = 0; nt < 10; nt++)
#pragma unroll
      for (int rg = 0; rg < 4; rg++) {
        int qq = rt * 16 + lg * 4 + rg;
        int j = nt * 16 + lr;
        bool valid = (j >= qq) && (j <= qq + 127) && ((kb + j) >= 0);
        sc[rt][nt][rg] = valid ? sc[rt][nt][rg] * SCALE : NEGINF;
      }

  const float sink = sinks[head];
  float den[2][4];
#pragma unroll
  for (int rt = 0; rt < 2; rt++)
#pragma unroll
    for (int rg = 0; rg < 4; rg++) {
      float m = NEGINF;
#pragma unroll
      for (int nt = 0; nt < 10; nt++) m = fmaxf(m, sc[rt][nt][rg]);
#pragma unroll
      for (int x = 1; x < 16; x <<= 1) m = fmaxf(m, __shfl_xor(m, x, 64));
      m = fmaxf(m, sink);
      float sum = 0.f;
#pragma unroll
      for (int nt = 0; nt < 10; nt++) {
        float p = __expf(sc[rt][nt][rg] - m);
        sc[rt][nt][rg] = p;
        sum += p;
      }
#pragma unroll
      for (int x = 1; x < 16; x <<= 1) sum += __shfl_xor(sum, x, 64);
      den[rt][rg] = sum + __expf(sink - m);
    }

  f32x4 oacc[2][4];
#pragma unroll
  for (int rt = 0; rt < 2; rt++)
#pragma unroll
    for (int dn = 0; dn < 4; dn++) oacc[rt][dn] = zz;
  u16* slab = &Pslab[w * 32 * 40];
#pragma unroll
  for (int kt = 0; kt < 5; kt++) {
#pragma unroll
    for (int rt = 0; rt < 2; rt++)
#pragma unroll
      for (int j2 = 0; j2 < 2; j2++)
#pragma unroll
        for (int rg = 0; rg < 4; rg++)
          slab[(rt * 16 + lg * 4 + rg) * 40 + j2 * 16 + lr] = f2bf(sc[rt][kt * 2 + j2][rg]);
    asm volatile("s_waitcnt lgkmcnt(0)" ::: "memory");
    __builtin_amdgcn_sched_barrier(0);
    bf16x8 pf0 = *(const bf16x8*)&slab[lr * 40 + lg * 8];
    bf16x8 pf1 = *(const bf16x8*)&slab[(16 + lr) * 40 + lg * 8];
#pragma unroll
    for (int dn = 0; dn < 4; dn++) {
      bf16x8 vf = *(const bf16x8*)&Vt[(dn * 16 + lr) * 168 + kt * 32 + lg * 8];
      oacc[0][dn] = MFMA16(pf0, vf, oacc[0][dn]);
      oacc[1][dn] = MFMA16(pf1, vf, oacc[1][dn]);
    }
  }

#pragma unroll
  for (int rt = 0; rt < 2; rt++)
#pragma unroll
    for (int dn = 0; dn < 4; dn++)
#pragma unroll
      for (int rg = 0; rg < 4; rg++) {
        int s = s0 + rt * 16 + lg * 4 + rg;
        float val = oacc[rt][dn][rg] / den[rt][rg];
        out[(size_t)s * ATTN_K + head * 64 + dn * 16 + lr] = f2bf(val);
      }
}

extern "C" void kernel_launch(void* const* d_in, const int* in_sizes, int n_in,
                              void* d_out, int out_size, void* d_ws, size_t ws_size,
                              hipStream_t stream) {
  const float* hs = (const float*)d_in[0];
  const int* pos = (const int*)d_in[1];
  const float* wqkv = (const float*)d_in[2];
  const float* bqkv = (const float*)d_in[3];
  const float* wo = (const float*)d_in[4];
  const float* bo = (const float*)d_in[5];
  const float* sinks = (const float*)d_in[6];
  float* out = (float*)d_out;

  char* ws = (char*)d_ws;
  u16* qkvb = (u16*)(ws + 0);               // 2048*5120*2 = 20,971,520 (bf16 now)
  u16* hsb = (u16*)(ws + 41943040);         // 2048*2944*2 = 12,058,624
  u16* wqkvT = (u16*)(ws + 54001664);       // 5120*2944*2 = 30,146,560 -> ends 84,148,224
  u16* attnb = (u16*)(ws + 41943040);       // 2048*4096*2 (aliases dead hsb/wqkvT)
  u16* woT = (u16*)(ws + 84148224);         // 2944*4096*2 = 24,117,248 -> ends 108,265,472
  float2* tab = (float2*)(ws + 108265472);  // 2048*32*8   = 524,288

  k_rope_table<<<256, 256, 0, stream>>>(pos, tab);
  k_convert_pad<<<5888, 256, 0, stream>>>(hs, hsb);
  k_transpose<<<dim3(160, 92), 256, 0, stream>>>(wqkv, wqkvT, 2880, KPAD, 5120, 5120);
  k_transpose<<<dim3(92, 128), 256, 0, stream>>>(wo, woT, 4096, 4096, 2880, 2944);
  k_gemm1<<<160, 512, 0, stream>>>(hsb, wqkvT, bqkv, tab, qkvb);
  k_attn<<<dim3(64, 8), 512, 0, stream>>>(qkvb, sinks, attnb);
  k_gemm2<<<368, 256, 0, stream>>>(attnb, woT, bo, out);
}